// Round 1
// baseline (1314.510 us; speedup 1.0000x reference)
//
#include <hip/hip_runtime.h>
#include <stdint.h>

#define VOCAB 50257
#define DM 768
#define SEQ 2048

typedef int int4v  __attribute__((ext_vector_type(4)));
typedef int int16v __attribute__((ext_vector_type(16)));

// ---------------- prepass 1: elementwise int32 -> int8 (packed 4/thread) ----
__global__ __launch_bounds__(256) void k_narrow(const int* __restrict__ src,
                                                signed char* __restrict__ dst,
                                                int n4) {
  int i = blockIdx.x * 256 + threadIdx.x;
  if (i >= n4) return;
  int4v v = ((const int4v*)src)[i];
  unsigned packed = (unsigned)(v[0] & 0xff)
                  | ((unsigned)(v[1] & 0xff) << 8)
                  | ((unsigned)(v[2] & 0xff) << 16)
                  | ((unsigned)(v[3] & 0xff) << 24);
  ((unsigned*)dst)[i] = packed;
}

// ---------------- prepass 2: lm_head [768][V] i32 -> BT [V][768] i8 ---------
__global__ __launch_bounds__(256) void k_transpose(const int* __restrict__ lm,
                                                   signed char* __restrict__ bt) {
  __shared__ signed char tile[64 * 66];   // stride 66 to spread banks on gather
  const int t  = threadIdx.x;
  const int v0 = blockIdx.x * 64;
  const int k0 = blockIdx.y * 64;
  {
    const int c  = t & 63;
    const int r0 = (t >> 6) * 16;
    int vc = v0 + c; if (vc > VOCAB - 1) vc = VOCAB - 1;
    const int* p = lm + (long)(k0 + r0) * VOCAB + vc;
#pragma unroll
    for (int i = 0; i < 16; ++i)
      tile[(r0 + i) * 66 + c] = (signed char)p[(long)i * VOCAB];
  }
  __syncthreads();
  const int vl = t >> 2;
  const int pc = t & 3;
  const int vg = v0 + vl;
  if (vg >= VOCAB) return;
  unsigned w[4];
#pragma unroll
  for (int d = 0; d < 4; ++d) {
    unsigned acc = 0;
#pragma unroll
    for (int b = 0; b < 4; ++b)
      acc |= (unsigned)(tile[(pc * 16 + d * 4 + b) * 66 + vl] & 0xff) << (8 * b);
    w[d] = acc;
  }
  int4v o = { (int)w[0], (int)w[1], (int)w[2], (int)w[3] };
  *(int4v*)(bt + (long)vg * DM + k0 + pc * 16) = o;
}

// ---------------- fused merged-batch int8 GEMM ------------------------------
// Block: 256 thr (4 waves). Tile: s-tile 64 positions x 128 vocab cols.
// 3 sub-tiles (tok0, tok1, pos) of 64x128 share one B tile; epilogue fuses
// out_b = tok_b + pos + bias. MFMA: i32_32x32x32_i8.
// Wave w -> (mt = w&1: 32-row half, nh = w>>1: 64-col half) of each sub-tile.
#define LDS_B_OFF 12288

#define GLL(gsrc, loff)                                                        \
  __builtin_amdgcn_global_load_lds(                                           \
      (const __attribute__((address_space(1))) void*)(gsrc),                   \
      (__attribute__((address_space(3))) void*)(smem + (loff)), 16, 0, 0)

__global__ __launch_bounds__(256, 2) void k_gemm(
    const int* __restrict__ ids, const signed char* __restrict__ bt8,
    const signed char* __restrict__ wte8, const signed char* __restrict__ wpe8,
    const int* __restrict__ bias, int* __restrict__ out) {
  __shared__ signed char smem[20480];   // A: 3*4096 (192 rows x 64B), B: 128x64B
  const int t  = threadIdx.x;
  const int n0 = blockIdx.x * 128;
  const int s0 = blockIdx.y * 64;
  const int lane = t & 63;
  const int wv   = t >> 6;

  // ---- staging setup: thread t covers row (t>>2), swizzled 16B chunk ----
  const int srow = t >> 2;                               // 0..63
  const int g16  = (((t & 3) ^ ((t >> 3) & 3)) << 4);    // XOR-swizzled chunk
  const int id0 = ids[s0 + srow];
  const int id1 = ids[SEQ + s0 + srow];
  const signed char* ga0 = wte8 + (long)id0 * DM + g16;
  const signed char* ga1 = wte8 + (long)id1 * DM + g16;
  const signed char* ga2 = wpe8 + (long)(s0 + srow) * DM + g16;
  int c0 = n0 + srow;      if (c0 > VOCAB - 1) c0 = VOCAB - 1;
  int c1 = n0 + 64 + srow; if (c1 > VOCAB - 1) c1 = VOCAB - 1;
  const signed char* gb0 = bt8 + (long)c0 * DM + g16;
  const signed char* gb1 = bt8 + (long)c1 * DM + g16;
  const unsigned dstW = wv * 1024;   // wave-uniform LDS base per instr

  // ---- fragment LDS offsets (A: m=lane&31, k=(lane>>5)*16+j) ----
  const int mt   = wv & 1;
  const int nh   = wv >> 1;
  const int agrp = lane >> 5;
  const int am   = mt * 32 + (lane & 31);
  int aoff[2][3], boff[2][2];
#pragma unroll
  for (int kk = 0; kk < 2; ++kk) {
    const int ch = kk * 2 + agrp;                        // 16B chunk index in k
#pragma unroll
    for (int sub = 0; sub < 3; ++sub)
      aoff[kk][sub] = sub * 4096 + am * 64 + ((ch ^ ((am >> 1) & 3)) << 4);
#pragma unroll
    for (int nt = 0; nt < 2; ++nt) {
      const int nl = nh * 64 + nt * 32 + (lane & 31);
      boff[kk][nt] = LDS_B_OFF + nl * 64 + ((ch ^ ((nl >> 1) & 3)) << 4);
    }
  }

  int16v acc[3][2] = {};

  for (int step = 0; step < 12; ++step) {
    const int k0 = step * 64;
    GLL(ga0 + k0, 0 + dstW);
    GLL(ga1 + k0, 4096 + dstW);
    GLL(ga2 + k0, 8192 + dstW);
    GLL(gb0 + k0, LDS_B_OFF + dstW);
    GLL(gb1 + k0, LDS_B_OFF + 4096 + dstW);
    __syncthreads();   // compiler drains vmcnt(0) here -> staging visible
#pragma unroll
    for (int kk = 0; kk < 2; ++kk) {
      int4v b0 = *(const int4v*)(smem + boff[kk][0]);
      int4v b1 = *(const int4v*)(smem + boff[kk][1]);
#pragma unroll
      for (int sub = 0; sub < 3; ++sub) {
        int4v a = *(const int4v*)(smem + aoff[kk][sub]);
        acc[sub][0] = __builtin_amdgcn_mfma_i32_32x32x32_i8(a, b0, acc[sub][0], 0, 0, 0);
        acc[sub][1] = __builtin_amdgcn_mfma_i32_32x32x32_i8(a, b1, acc[sub][1], 0, 0, 0);
      }
    }
    __syncthreads();   // protect LDS before next stage overwrites
  }

  // ---- epilogue: out_b = tok_b + pos + bias; C/D: col=lane&31,
  //      row = (reg&3) + 4*(lane>>5) + 8*(reg>>2) ----
#pragma unroll
  for (int nt = 0; nt < 2; ++nt) {
    const int colg = n0 + nh * 64 + nt * 32 + (lane & 31);
    if (colg >= VOCAB) continue;
    const int bv = bias[colg];
    const int r0 = s0 + mt * 32 + 4 * agrp;
#pragma unroll
    for (int r = 0; r < 16; ++r) {
      const int row = r0 + (r & 3) + 8 * (r >> 2);
      const long off = (long)row * VOCAB + colg;
      const int pv = acc[2][nt][r];
      out[off]                      = acc[0][nt][r] + pv + bv;
      out[off + (long)SEQ * VOCAB]  = acc[1][nt][r] + pv + bv;
    }
  }
}

extern "C" void kernel_launch(void* const* d_in, const int* in_sizes, int n_in,
                              void* d_out, int out_size, void* d_ws, size_t ws_size,
                              hipStream_t stream) {
  const int* ids  = (const int*)d_in[0];   // [2,2048]
  const int* wte  = (const int*)d_in[1];   // [50257,768] (int8 values as i32)
  const int* wpe  = (const int*)d_in[2];   // [2048,768]
  const int* lm   = (const int*)d_in[3];   // [768,50257]
  const int* bias = (const int*)d_in[4];   // [50257]
  int* out = (int*)d_out;

  signed char* ws   = (signed char*)d_ws;  // needs 2*38,597,376 + 1,572,864 B
  signed char* bt8  = ws;                                  // [V][768] i8
  signed char* wte8 = ws + (size_t)VOCAB * DM;             // [V][768] i8
  signed char* wpe8 = ws + 2 * (size_t)VOCAB * DM;         // [2048][768] i8

  const int n4_wte = VOCAB * DM / 4;
  const int n4_wpe = SEQ * DM / 4;
  k_narrow<<<(n4_wte + 255) / 256, 256, 0, stream>>>(wte, wte8, n4_wte);
  k_narrow<<<(n4_wpe + 255) / 256, 256, 0, stream>>>(wpe, wpe8, n4_wpe);
  k_transpose<<<dim3((VOCAB + 63) / 64, DM / 64), 256, 0, stream>>>(lm, bt8);
  k_gemm<<<dim3((VOCAB + 127) / 128, SEQ / 64), 256, 0, stream>>>(
      ids, bt8, wte8, wpe8, bias, out);
}